// Round 8
// baseline (440.372 us; speedup 1.0000x reference)
//
#include <hip/hip_runtime.h>

#define CC 32
#define HH 256
#define WW 512
#define HWSZ (HH*WW)          // 131072
#define BB 4
#define NIMG 8                // 2 sides * 4 batch, img = side*4 + b
#define EPS 1e-5f
#define MAXD 48

// conv act tile: 8x64 outputs + halo of 1 -> 10 x 66 blocks per channel-octet
#define ACT_R 10
#define ACT_C 66
#define ACT_USED (ACT_R*ACT_C)   // 660
#define ACT_STR 704              // 660 rounded to 11*64 (global_load_lds tail pad)

typedef __attribute__((ext_vector_type(8))) short short8;    // 16B = 8 bf16
typedef __attribute__((ext_vector_type(4))) short short4v;   // 8B = 4 bf16
typedef __attribute__((ext_vector_type(16))) float f32x16;

typedef __attribute__((address_space(1))) const unsigned int g_u32;
typedef __attribute__((address_space(3))) unsigned int l_u32;

__device__ __forceinline__ void gl_lds16(const void* g, void* l) {
  // async global->LDS DMA, 16B per lane; LDS dest = wave-uniform base + lane*16
  __builtin_amdgcn_global_load_lds((g_u32*)g, (l_u32*)l, 16, 0, 0);
}

__device__ inline unsigned short f2bf(float f) {
  unsigned int b = __builtin_bit_cast(unsigned int, f);
  b += 0x7FFFu + ((b >> 16) & 1u);        // round-to-nearest-even
  return (unsigned short)(b >> 16);
}
__device__ inline float bf2f(short s) {
  unsigned int u = ((unsigned int)(unsigned short)s) << 16;
  return __builtin_bit_cast(float, u);
}

// ---- weight pre-swizzle: OIHW fp32 -> [which][((s*2+t)*2+lh)*32+ln] short8 ----
__global__ __launch_bounds__(256) void wxpose_k(
    const float* __restrict__ w1, const float* __restrict__ w2,
    short8* __restrict__ wtr)
{
  int e = blockIdx.x * 256 + threadIdx.x;
  if (e >= 2304) return;
  int which = e >= 1152;
  int i = e - which * 1152;
  const float* w = which ? w2 : w1;
  int ln = i & 31, lh = (i >> 5) & 1, t = (i >> 6) & 1, s = i >> 7;
  short8 v;
  #pragma unroll
  for (int j = 0; j < 8; ++j)
    v[j] = (short)f2bf(w[(size_t)(ln * CC + t * 16 + lh * 8 + j) * 9 + s]);
  wtr[e] = v;
}

// ---- input transpose: fp32 NCHW -> bf16 NHWC [img][y][x][c] ----
__global__ __launch_bounds__(256) void xpose_k(
    const float* __restrict__ inL, const float* __restrict__ inR,
    short8* __restrict__ xin)
{
  const int img = blockIdx.x >> 8;
  const int y   = blockIdx.x & 255;
  const int g   = threadIdx.x >> 6;      // channel octet (wave id)
  const int xl  = threadIdx.x & 63;
  const float* src = (img < BB ? inL : inR) + (size_t)(img & 3) * CC * HWSZ + (size_t)y * WW;
  short8* dst = xin + ((size_t)img * HH + y) * WW * 4;
  #pragma unroll
  for (int xc = 0; xc < 8; ++xc) {
    int x = xc * 64 + xl;
    short8 v;
    #pragma unroll
    for (int j = 0; j < 8; ++j)
      v[j] = (short)f2bf(src[(size_t)(g * 8 + j) * HWSZ + x]);
    dst[(size_t)x * 4 + g] = v;
  }
}

// ---- BN+ReLU elementwise on bf16 NHWC: yn = relu(y*scale+shift) ----
__global__ __launch_bounds__(256) void norm_k(
    const short8* __restrict__ y, const float* __restrict__ scale,
    const float* __restrict__ shift, short8* __restrict__ yn)
{
  const size_t tid = (size_t)blockIdx.x * 256 + threadIdx.x;  // 524288 threads
  #pragma unroll
  for (int k = 0; k < 8; ++k) {
    const size_t p = (size_t)k * 524288 + tid;   // block index, img = p>>19
    const int side = (int)(p >> 21);             // img>>2  (img = p>>19, 4 imgs/side)
    const int g    = (int)(p & 3);
    const int cb   = side * CC + g * 8;
    short8 v = y[p];
    #pragma unroll
    for (int j = 0; j < 8; ++j)
      v[j] = (short)f2bf(fmaxf(fmaf(bf2f(v[j]), scale[cb + j], shift[cb + j]), 0.f));
    yn[p] = v;
  }
}

// ---- implicit-GEMM 3x3 conv (pad 1) on bf16 NHWC, v_mfma_f32_32x32x16_bf16 ----
// Staging is pure global_load_lds (async DMA): per wave 11 issues, LDS layout is
// e-linear (e = i*64+lane -> r = e/66, c = e%66). OOB lanes read a zero page.
__global__ __launch_bounds__(256, 3) void conv_k(
    const short8* __restrict__ xin, const short8* __restrict__ wtab,
    const short8* __restrict__ zpage,
    short8* __restrict__ yout, float* __restrict__ ssum, float* __restrict__ ssq)
{
  __shared__ short8 actb[4 * ACT_STR];   // 45056 B (660 used + 44 pad per octet)
  __shared__ float  sred[256];           // 1024 B cross-wave stats

  const int tid  = threadIdx.x;
  const int img  = blockIdx.x >> 8;
  const int rem  = blockIdx.x & 255;
  const int y0   = (rem >> 3) * 8;
  const int x0   = (rem & 7) * 64;
  const int side = img >> 2;
  const int wid  = tid >> 6;
  const int lane = tid & 63;

  const short8* srcimg = xin + (size_t)img * HH * WW * 4;
  #pragma unroll
  for (int i = 0; i < 11; ++i) {
    const int e = i * 64 + lane;
    const int r = e / ACT_C;
    const int c = e - r * ACT_C;
    const int yy = y0 - 1 + r;
    const int xx = x0 - 1 + c;
    const bool ok = (e < ACT_USED) & ((unsigned)yy < (unsigned)HH) & ((unsigned)xx < (unsigned)WW);
    const short8* src = ok ? &srcimg[((size_t)yy * WW + xx) * 4 + wid] : zpage;
    gl_lds16(src, &actb[wid * ACT_STR + i * 64]);      // + lane*16 by HW
  }
  __syncthreads();

  const int wr = wid >> 1;
  const int wc = wid & 1;
  const int lh = lane >> 5;
  const int ln = lane & 31;
  const int cbase = wc * 32 + ln;

  f32x16 acc[4];
  #pragma unroll
  for (int o = 0; o < 4; ++o)
    #pragma unroll
    for (int i = 0; i < 16; ++i) acc[o][i] = 0.f;

  #pragma unroll
  for (int t = 0; t < 2; ++t) {
    short8 afr[9];
    #pragma unroll
    for (int s = 0; s < 9; ++s)
      afr[s] = wtab[((s * 2 + t) * 2 + lh) * 32 + ln];
    #pragma unroll
    for (int irow = 0; irow < 6; ++irow) {
      const int rr = wr * 4 + irow;
      #pragma unroll
      for (int kx = 0; kx < 3; ++kx) {
        short8 b = actb[(t * 2 + lh) * ACT_STR + rr * ACT_C + cbase + kx];
        #pragma unroll
        for (int ky = 0; ky < 3; ++ky) {
          const int o = irow - ky;
          if (o >= 0 && o <= 3) {
            acc[o] = __builtin_amdgcn_mfma_f32_32x32x16_bf16(
                       afr[ky * 3 + kx], b, acc[o], 0, 0, 0);
          }
        }
      }
    }
  }

  // ---- write bf16 NHWC output. C/D: col=ln, co=(r16&3)+8*(r16>>2)+4*lh ----
  const int ox = x0 + wc * 32 + ln;
  short4v* yb = (short4v*)yout;
  #pragma unroll
  for (int o = 0; o < 4; ++o) {
    const int oy = y0 + wr * 4 + o;
    const size_t pix = ((size_t)img * HH + oy) * WW + ox;
    #pragma unroll
    for (int qq = 0; qq < 4; ++qq) {        // co run = qq*8 + lh*4 .. +3
      short4v z;
      #pragma unroll
      for (int m = 0; m < 4; ++m) z[m] = (short)f2bf(acc[o][qq * 4 + m]);
      yb[pix * 8 + qq * 2 + lh] = z;
    }
  }

  // ---- BN stats: row-reduce, 32-lane xor-reduce, cross-wave, atomics ----
  float s16[16], q16[16];
  #pragma unroll
  for (int r16 = 0; r16 < 16; ++r16) {
    float s = 0.f, q = 0.f;
    #pragma unroll
    for (int o = 0; o < 4; ++o) { float v = acc[o][r16]; s += v; q += v * v; }
    #pragma unroll
    for (int off = 16; off >= 1; off >>= 1) {
      s += __shfl_xor(s, off);
      q += __shfl_xor(q, off);
    }
    s16[r16] = s; q16[r16] = q;
  }
  if (ln == 0) {
    #pragma unroll
    for (int r16 = 0; r16 < 16; ++r16) {
      const int co = (r16 & 3) + 8 * (r16 >> 2) + 4 * lh;
      sred[wid * 64 + co]      = s16[r16];
      sred[wid * 64 + 32 + co] = q16[r16];
    }
  }
  __syncthreads();
  if (tid < 64) {
    float v = sred[tid] + sred[64 + tid] + sred[128 + tid] + sred[192 + tid];
    if (tid < 32) atomicAdd(&ssum[side * CC + tid], v);
    else          atomicAdd(&ssq [side * CC + tid - 32], v);
  }
}

// ---- BN finalize ----
__global__ __launch_bounds__(64) void bnfin_k(
    const float* __restrict__ ssum, const float* __restrict__ ssq,
    const float* __restrict__ gamma, const float* __restrict__ beta,
    float* __restrict__ scale, float* __restrict__ shift)
{
  int t = threadIdx.x;            // 2 sides * 32 ch
  int c = t & 31;
  const float n = (float)(BB * HWSZ);
  float m  = ssum[t] / n;
  float vr = ssq[t] / n - m * m;
  float sc = gamma[c] * rsqrtf(vr + EPS);
  scale[t] = sc;
  shift[t] = beta[c] - m * sc;
}

// ---- fused: BN2+ReLU -> g2 1x1 conv -> weight volume (both dirs) -> blend ----
__global__ __launch_bounds__(256, 2) void ffinal_k(
    const short8* __restrict__ y2, const float* __restrict__ scale, const float* __restrict__ shift,
    const float* __restrict__ g2w, const float* __restrict__ g2b,
    const float* __restrict__ left, const float* __restrict__ right,
    float* __restrict__ out)
{
  __shared__ short8 zb[2][WW][4];   // 65536 B: relu(bn(y2)) both sides
  __shared__ float g2r[2][WW];      // 4096 B: g2 rows

  const int b   = blockIdx.x >> 8;
  const int h   = blockIdx.x & 255;
  const int tid = threadIdx.x;

  float wreg[32];
  #pragma unroll
  for (int g = 0; g < 8; ++g) {
    float4 t4 = *(const float4*)&g2w[g * 4];
    wreg[g * 4] = t4.x; wreg[g * 4 + 1] = t4.y; wreg[g * 4 + 2] = t4.z; wreg[g * 4 + 3] = t4.w;
  }
  const float g2b0 = g2b[0];

  #pragma unroll
  for (int side = 0; side < 2; ++side) {
    float scs[32], shs[32];
    #pragma unroll
    for (int g = 0; g < 8; ++g) {
      float4 a = *(const float4*)&scale[side * CC + g * 4];
      float4 c4 = *(const float4*)&shift[side * CC + g * 4];
      scs[g * 4] = a.x; scs[g * 4 + 1] = a.y; scs[g * 4 + 2] = a.z; scs[g * 4 + 3] = a.w;
      shs[g * 4] = c4.x; shs[g * 4 + 1] = c4.y; shs[g * 4 + 2] = c4.z; shs[g * 4 + 3] = c4.w;
    }
    const int img = side * BB + b;
    #pragma unroll
    for (int it = 0; it < 2; ++it) {
      const int x = it * 256 + tid;
      const size_t pixb = (((size_t)img * HH + h) * WW + x) * 4;
      float d = g2b0;
      #pragma unroll
      for (int g = 0; g < 4; ++g) {
        short8 v = y2[pixb + g];
        short8 z;
        #pragma unroll
        for (int j = 0; j < 8; ++j) {
          float f = fmaxf(fmaf(bf2f(v[j]), scs[g * 8 + j], shs[g * 8 + j]), 0.f);
          d += f * wreg[g * 8 + j];
          z[j] = (short)f2bf(f);
        }
        zb[side][x][g] = z;
      }
      g2r[side][x] = d;
    }
  }
  __syncthreads();

  const size_t OUT_R = (size_t)BB * CC * HWSZ;
  #pragma unroll
  for (int it = 0; it < 2; ++it) {
    const int x = it * 256 + tid;
    const float Lv = g2r[0][x], Rv = g2r[1][x];
    float vL = 1e30f, vR = 1e30f;
    const int lo = (x - MAXD < 0) ? 0 : (x - MAXD);
    const int hi = (x + MAXD - 1 > WW - 1) ? (WW - 1) : (x + MAXD - 1);
    for (int idx = lo; idx <= hi; ++idx) {
      vL = fminf(vL, fabsf(g2r[1][idx] - Lv));
      vR = fminf(vR, fabsf(g2r[0][idx] - Rv));
    }
    const float wL = 1.f / (1.f + __expf(vL));
    const float wR = 1.f / (1.f + __expf(vR));

    #pragma unroll
    for (int side = 0; side < 2; ++side) {
      const float wgt = side ? wR : wL;
      const float* inp = (side ? right : left) + (size_t)b * CC * HWSZ + (size_t)h * WW + x;
      float* op = out + (side ? OUT_R : 0) + (size_t)b * CC * HWSZ + (size_t)h * WW + x;
      short8 zz[4];
      #pragma unroll
      for (int g = 0; g < 4; ++g) zz[g] = zb[side][x][g];
      #pragma unroll
      for (int g = 0; g < 4; ++g)
        #pragma unroll
        for (int j = 0; j < 8; ++j) {
          const int c = g * 8 + j;
          op[(size_t)c * HWSZ] = bf2f(zz[g][j]) * wgt + inp[(size_t)c * HWSZ];
        }
    }
  }
}

extern "C" void kernel_launch(void* const* d_in, const int* in_sizes, int n_in,
                              void* d_out, int out_size, void* d_ws, size_t ws_size,
                              hipStream_t stream)
{
  const float* left  = (const float*)d_in[0];
  const float* right = (const float*)d_in[1];
  const float* w1    = (const float*)d_in[2];
  const float* bn1g  = (const float*)d_in[3];
  const float* bn1b  = (const float*)d_in[4];
  const float* w2    = (const float*)d_in[5];
  const float* bn2g  = (const float*)d_in[6];
  const float* bn2b  = (const float*)d_in[7];
  const float* g2w   = (const float*)d_in[8];
  const float* g2b   = (const float*)d_in[9];
  float* out = (float*)d_out;

  const size_t NB = (size_t)NIMG * HH * WW * 4;   // short8 blocks per NHWC tensor
  short8* xin  = (short8*)d_ws;
  short8* y1   = xin + NB;
  short8* y1n  = y1 + NB;
  short8* y2   = y1n + NB;
  short8* wtr  = y2 + NB;                         // 2304 blocks (w1 then w2)
  float* stats = (float*)(wtr + 2304);            // 512 floats
  short8* zpage = (short8*)(stats + 512);         // 64 B zero page (16B-aligned)

  float* sum1 = stats;       float* sq1 = stats + 64;
  float* sum2 = stats + 128; float* sq2 = stats + 192;
  float* sc1  = stats + 256; float* sh1 = stats + 320;
  float* sc2  = stats + 384; float* sh2 = stats + 448;

  hipMemsetAsync(stats, 0, 512 * sizeof(float) + 64, stream);   // stats + zero page

  wxpose_k<<<9, 256, 0, stream>>>(w1, w2, wtr);
  xpose_k<<<2048, 256, 0, stream>>>(left, right, xin);
  conv_k<<<2048, 256, 0, stream>>>(xin, wtr, zpage, y1, sum1, sq1);
  bnfin_k<<<1, 64, 0, stream>>>(sum1, sq1, bn1g, bn1b, sc1, sh1);
  norm_k<<<2048, 256, 0, stream>>>(y1, sc1, sh1, y1n);
  conv_k<<<2048, 256, 0, stream>>>(y1n, wtr + 1152, zpage, y2, sum2, sq2);
  bnfin_k<<<1, 64, 0, stream>>>(sum2, sq2, bn2g, bn2b, sc2, sh2);
  ffinal_k<<<1024, 256, 0, stream>>>(y2, sc2, sh2, g2w, g2b, left, right, out);
}